// Round 3
// baseline (206.738 us; speedup 1.0000x reference)
//
#include <hip/hip_runtime.h>

// DeQuantizer: 4-bit GPTQ-style weight dequantization.
// qweight: int32 [K/8, N], qzeros: int32 [G, N/8], scales: f32 [G, N],
// g_idx: int32 [K] (sorted). out: f32 [K, N].
// out[k][n] = scales[g][n] * (((qw[k/8][n] >> 4*(k%8)) & 15) - ((qz[g][n/8] >> 4*(n%8)) & 15))
// with g = g_idx[k].

#define KK 4096
#define NN 11008
#define GROUPS 32
#define NPACK (NN / 8)   // 1376
#define KPACKS (KK / 8)  // 512
#define N4 (NN / 4)      // 2752

// clang native vectors — required by __builtin_nontemporal_{load,store}
typedef int   iv4 __attribute__((ext_vector_type(4)));
typedef float fv4 __attribute__((ext_vector_type(4)));

__global__ __launch_bounds__(256) void dequant_kernel(
    const int* __restrict__ qweight,   // [512, N]
    const int* __restrict__ qzeros,    // [32, 1376]
    const float* __restrict__ scales,  // [32, N]
    const int* __restrict__ g_idx,     // [K]
    float* __restrict__ out)           // [K, N]
{
    const int kp = blockIdx.y;                         // rows kp*8 .. kp*8+7
    const int base = blockIdx.x * 512 + threadIdx.x;   // first n4 of this thread

    // group ids for the 8 rows of this pack (block-uniform -> scalar loads)
    const iv4 ga = *reinterpret_cast<const iv4*>(&g_idx[kp * 8]);
    const iv4 gb = *reinterpret_cast<const iv4*>(&g_idx[kp * 8 + 4]);
    const int gs[8] = {ga.x, ga.y, ga.z, ga.w, gb.x, gb.y, gb.z, gb.w};
    // wave-uniform: all 8 rows in one quant group? (true for ~94% of packs)
    const bool uniform = (ga.x == ga.y) & (ga.x == ga.z) & (ga.x == ga.w) &
                         (ga.x == gb.x) & (ga.x == gb.y) & (ga.x == gb.z) &
                         (ga.x == gb.w);

    #pragma unroll
    for (int it = 0; it < 2; ++it) {
        const int n4 = base + it * 256;  // second item offset +256 keeps stores
        if (n4 >= N4) continue;          // 64-lane contiguous per instruction
        const int n = n4 * 4;

        // 4 packed-weight words (columns n..n+3 of pack-row kp), streamed once
        const iv4 qw = __builtin_nontemporal_load(
            reinterpret_cast<const iv4*>(&qweight[kp * NN + n]));

        // zeros for cols n..n+3: nibbles (n%8)..(n%8)+3 of word n/8
        const int zsh = (n & 4) * 4;
        const int zword = n >> 3;
        float* outp = &out[(size_t)kp * 8 * NN + n];

        if (uniform) {
            const int g = gs[0];
            const int zq = qzeros[g * NPACK + zword] >> zsh;
            const fv4 s = *reinterpret_cast<const fv4*>(&scales[g * NN + n]);
            // c = -s * z  (so per element: out = fma(s, w, c))
            const float cx = -s.x * (float)((zq      ) & 15);
            const float cy = -s.y * (float)((zq >>  4) & 15);
            const float cz = -s.z * (float)((zq >>  8) & 15);
            const float cw = -s.w * (float)((zq >> 12) & 15);

            #pragma unroll
            for (int j = 0; j < 8; ++j) {
                const int sh = 4 * j;
                fv4 o;
                o.x = fmaf(s.x, (float)((qw.x >> sh) & 15), cx);
                o.y = fmaf(s.y, (float)((qw.y >> sh) & 15), cy);
                o.z = fmaf(s.z, (float)((qw.z >> sh) & 15), cz);
                o.w = fmaf(s.w, (float)((qw.w >> sh) & 15), cw);
                __builtin_nontemporal_store(o,
                    reinterpret_cast<fv4*>(outp + (size_t)j * NN));
            }
        } else {
            #pragma unroll
            for (int j = 0; j < 8; ++j) {
                const int g = gs[j];
                const int zq = qzeros[g * NPACK + zword] >> zsh;
                const fv4 s = *reinterpret_cast<const fv4*>(&scales[g * NN + n]);
                const int sh = 4 * j;
                fv4 o;
                o.x = s.x * ((float)((qw.x >> sh) & 15) - (float)((zq      ) & 15));
                o.y = s.y * ((float)((qw.y >> sh) & 15) - (float)((zq >>  4) & 15));
                o.z = s.z * ((float)((qw.z >> sh) & 15) - (float)((zq >>  8) & 15));
                o.w = s.w * ((float)((qw.w >> sh) & 15) - (float)((zq >> 12) & 15));
                __builtin_nontemporal_store(o,
                    reinterpret_cast<fv4*>(outp + (size_t)j * NN));
            }
        }
    }
}

extern "C" void kernel_launch(void* const* d_in, const int* in_sizes, int n_in,
                              void* d_out, int out_size, void* d_ws, size_t ws_size,
                              hipStream_t stream) {
    const int*   qweight = (const int*)d_in[0];
    const int*   qzeros  = (const int*)d_in[1];
    const float* scales  = (const float*)d_in[2];
    const int*   g_idx   = (const int*)d_in[3];
    float*       out     = (float*)d_out;

    dim3 block(256);
    dim3 grid((N4 + 511) / 512, KPACKS);  // (6, 512): 2 items/thread
    dequant_kernel<<<grid, block, 0, stream>>>(qweight, qzeros, scales, g_idx, out);
}

// Round 4
// 204.804 us; speedup vs baseline: 1.0094x; 1.0094x over previous
//
#include <hip/hip_runtime.h>

// DeQuantizer: 4-bit GPTQ-style weight dequantization.
// qweight: int32 [K/8, N], qzeros: int32 [G, N/8], scales: f32 [G, N],
// g_idx: int32 [K] (sorted). out: f32 [K, N].
// out[k][n] = scales[g][n] * (((qw[k/8][n] >> 4*(k%8)) & 15) - ((qz[g][n/8] >> 4*(n%8)) & 15))
// with g = g_idx[k].
//
// Structure: one block per (column-half, k-pack). Block loads g_idx once,
// then sweeps 5-6 column chunks of 1024 floats, software-prefetching the
// next chunk's qweight words so each wave emits a continuous store train.

#define NN 11008
#define NPACK (NN / 8)   // 1376
#define KPACKS 512       // 4096 / 8

typedef int   iv4 __attribute__((ext_vector_type(4)));
typedef float fv4 __attribute__((ext_vector_type(4)));

__global__ __launch_bounds__(256) void dequant_kernel(
    const int* __restrict__ qweight,   // [512, N]
    const int* __restrict__ qzeros,    // [32, 1376]
    const float* __restrict__ scales,  // [32, N]
    const int* __restrict__ g_idx,     // [K]
    float* __restrict__ out)           // [K, N]
{
    const int kp   = blockIdx.y;        // rows kp*8 .. kp*8+7
    const int half = blockIdx.x;        // 0: chunks 0..4, 1: chunks 5..10
    const int c0   = half ? 5 : 0;
    const int nc   = half ? 6 : 5;
    const int tid  = threadIdx.x;

    // group ids for this pack's 8 rows (block-uniform -> scalar loads, once)
    const int g0 = g_idx[kp * 8 + 0];
    const int g7 = g_idx[kp * 8 + 7];
    int gs[8];
    #pragma unroll
    for (int j = 0; j < 8; ++j) gs[j] = g_idx[kp * 8 + j];
    // g_idx is sorted, so g0==g7 implies all 8 rows share one group (~94%)
    const bool uniform = (g0 == g7);

    const int*  qwrow  = &qweight[(size_t)kp * NN];
    float*      outrow = &out[(size_t)kp * 8 * NN];

    int  n     = c0 * 1024 + tid * 4;
    bool valid = (n < NN);
    iv4  qw    = {};
    if (valid) qw = __builtin_nontemporal_load(
                        reinterpret_cast<const iv4*>(qwrow + n));

    for (int i = 0; i < nc; ++i) {
        const int  ncur = n;
        const bool vcur = valid;
        const iv4  q    = qw;

        // software prefetch of next chunk's packed weights (one iter ahead)
        n += 1024;
        valid = (i + 1 < nc) && (n < NN);
        if (valid) qw = __builtin_nontemporal_load(
                            reinterpret_cast<const iv4*>(qwrow + n));

        if (!vcur) continue;   // only ragged-tail threads of the last chunk

        const int zsh = (ncur & 4) * 4;    // cols ncur..+3 -> nibbles of word
        const int zw  = ncur >> 3;

        if (uniform) {
            const int zq = qzeros[g0 * NPACK + zw] >> zsh;
            const fv4 s  = *reinterpret_cast<const fv4*>(&scales[g0 * NN + ncur]);
            const float cx = -s.x * (float)((zq      ) & 15);
            const float cy = -s.y * (float)((zq >>  4) & 15);
            const float cz = -s.z * (float)((zq >>  8) & 15);
            const float cw = -s.w * (float)((zq >> 12) & 15);

            #pragma unroll
            for (int j = 0; j < 8; ++j) {
                const int sh = 4 * j;
                fv4 o;
                o.x = fmaf(s.x, (float)((q.x >> sh) & 15), cx);
                o.y = fmaf(s.y, (float)((q.y >> sh) & 15), cy);
                o.z = fmaf(s.z, (float)((q.z >> sh) & 15), cz);
                o.w = fmaf(s.w, (float)((q.w >> sh) & 15), cw);
                *reinterpret_cast<fv4*>(outrow + (size_t)j * NN + ncur) = o;
            }
        } else {
            #pragma unroll
            for (int j = 0; j < 8; ++j) {
                const int g  = gs[j];
                const int zq = qzeros[g * NPACK + zw] >> zsh;
                const fv4 s  = *reinterpret_cast<const fv4*>(&scales[g * NN + ncur]);
                const int sh = 4 * j;
                fv4 o;
                o.x = s.x * ((float)((q.x >> sh) & 15) - (float)((zq      ) & 15));
                o.y = s.y * ((float)((q.y >> sh) & 15) - (float)((zq >>  4) & 15));
                o.z = s.z * ((float)((q.z >> sh) & 15) - (float)((zq >>  8) & 15));
                o.w = s.w * ((float)((q.w >> sh) & 15) - (float)((zq >> 12) & 15));
                *reinterpret_cast<fv4*>(outrow + (size_t)j * NN + ncur) = o;
            }
        }
    }
}

extern "C" void kernel_launch(void* const* d_in, const int* in_sizes, int n_in,
                              void* d_out, int out_size, void* d_ws, size_t ws_size,
                              hipStream_t stream) {
    const int*   qweight = (const int*)d_in[0];
    const int*   qzeros  = (const int*)d_in[1];
    const float* scales  = (const float*)d_in[2];
    const int*   g_idx   = (const int*)d_in[3];
    float*       out     = (float*)d_out;

    dim3 block(256);
    dim3 grid(2, KPACKS);   // (2, 512) = 1024 blocks, ~16 waves/CU resident
    dequant_kernel<<<grid, block, 0, stream>>>(qweight, qzeros, scales, g_idx, out);
}